// Round 3
// baseline (430.172 us; speedup 1.0000x reference)
//
#include <hip/hip_runtime.h>

typedef unsigned int u32;

// Problem shape
constexpr int B  = 2, C = 3, T = 5, H = 720, W = 1280;
constexpr int HW = H * W;
constexpr int W2 = W / 2;
constexpr int P2 = B * T * H * W2;        // one thread per horizontal pixel pair
constexpr int CH_STRIDE = T * HW;          // channel stride in x / f / out (fp32 elems)
constexpr int OUT_HALF  = B * C * T * HW;  // offset of second output (xw), fp32 elems

__global__ __launch_bounds__(256)
void bwarp_kernel(const float* __restrict__ x, const float* __restrict__ f,
                  float* __restrict__ out)
{
    int i = blockIdx.x * 256 + threadIdx.x;
    if (i >= P2) return;

    int w2 = i % W2;
    int r  = i / W2;
    int h  = r % H;
    int bt = r / H;           // b*T + t
    int b  = bt / T;
    int t  = bt - b * T;

    int plane = (b * 3 * T + t) * HW;          // channel-0 plane for x/f/out
    int base0 = plane + h * W + 2 * w2;        // even fp32 element index -> 8B aligned

    // coalesced 8B loads of flow_x, flow_y, weight-logit pairs (fp32)
    float2 fx2 = *(const float2*)(f + base0);
    float2 fy2 = *(const float2*)(f + base0 + CH_STRIDE);
    float2 fw2 = *(const float2*)(f + base0 + 2 * CH_STRIDE);

    float2 o0;
    float2 o1[3];

    #pragma unroll
    for (int j = 0; j < 2; ++j) {
        float fx = j ? fx2.y : fx2.x;
        float fy = j ? fy2.y : fy2.x;
        float fw = j ? fw2.y : fw2.x;

        // align_corners=True grid algebra collapses to pixel-space offsets:
        // gx = w + flow_x, gy = h + flow_y
        float gx = (float)(2 * w2 + j) + fx;
        float gy = (float)h + fy;

        float x0f = floorf(gx), y0f = floorf(gy);
        float wx1 = gx - x0f, wx0 = 1.0f - wx1;
        float wy1 = gy - y0f, wy0 = 1.0f - wy1;
        int x0 = (int)x0f, y0 = (int)y0f;
        int x1 = x0 + 1,   y1 = y0 + 1;

        // zeros padding: validity as multiplicative masks (branchless)
        float vx0 = (x0 >= 0 && x0 < W) ? 1.0f : 0.0f;
        float vx1 = (x1 >= 0 && x1 < W) ? 1.0f : 0.0f;
        float vy0 = (y0 >= 0 && y0 < H) ? 1.0f : 0.0f;
        float vy1 = (y1 >= 0 && y1 < H) ? 1.0f : 0.0f;

        int x0c = min(max(x0, 0), W - 1);
        int x1c = min(max(x1, 0), W - 1);
        int y0c = min(max(y0, 0), H - 1);
        int y1c = min(max(y1, 0), H - 1);

        float w00 = wx0 * wy0 * vx0 * vy0;
        float w10 = wx1 * wy0 * vx1 * vy0;
        float w01 = wx0 * wy1 * vx0 * vy1;
        float w11 = wx1 * wy1 * vx1 * vy1;

        float sigw = 1.0f / (1.0f + __expf(-fw));

        // backwarp(ones) * sigmoid(w)  -- identical across channels
        float s0 = (w00 + w10 + w01 + w11) * sigw;
        if (j) o0.y = s0; else o0.x = s0;

        int r0 = y0c * W, r1 = y1c * W;
        int a00 = r0 + x0c, a10 = r0 + x1c;
        int a01 = r1 + x0c, a11 = r1 + x1c;

        #pragma unroll
        for (int c = 0; c < 3; ++c) {
            const float* xp = x + plane + c * CH_STRIDE;
            float v = (w00 * xp[a00] + w10 * xp[a10]
                     + w01 * xp[a01] + w11 * xp[a11]) * sigw;
            if (j) o1[c].y = v; else o1[c].x = v;
        }
    }

    #pragma unroll
    for (int c = 0; c < 3; ++c) {
        *(float2*)(out + base0 + c * CH_STRIDE) = o0;                 // ow (same per ch)
        *(float2*)(out + OUT_HALF + base0 + c * CH_STRIDE) = o1[c];   // xw
    }
}

extern "C" void kernel_launch(void* const* d_in, const int* in_sizes, int n_in,
                              void* d_out, int out_size, void* d_ws, size_t ws_size,
                              hipStream_t stream) {
    const float* x = (const float*)d_in[0];
    const float* f = (const float*)d_in[1];
    float* out = (float*)d_out;
    int blocks = (P2 + 255) / 256;   // 18000
    bwarp_kernel<<<blocks, 256, 0, stream>>>(x, f, out);
}